// Round 1
// baseline (43897.278 us; speedup 1.0000x reference)
//
#include <hip/hip_runtime.h>
#include <hip/hip_bf16.h>

#define NN 250000
#define NE 1250000
#define NC 50000
#define EMBD 200

typedef unsigned int u32;
typedef unsigned short u16;

__device__ __forceinline__ float bf2f(u16 u) { return __uint_as_float(((u32)u) << 16); }
__device__ __forceinline__ u16 f2bf(float f) {
    u32 u = __float_as_uint(f);
    return (u16)((u + 0x7FFFu + ((u >> 16) & 1u)) >> 16);   // RNE
}
__device__ __forceinline__ float lrelu(float v) { return v > 0.f ? v : 0.01f * v; }
// order-preserving float<->uint for atomicMax; memset(0) == -inf sentinel
__device__ __forceinline__ u32 encf(float f) {
    u32 u = __float_as_uint(f);
    return (u & 0x80000000u) ? ~u : (u | 0x80000000u);
}
__device__ __forceinline__ float decf(u32 k) {
    return __uint_as_float((k & 0x80000000u) ? (k ^ 0x80000000u) : ~k);
}
__device__ __forceinline__ void unp8(uint4 v, float* f) {
    f[0] = __uint_as_float(v.x << 16); f[1] = __uint_as_float(v.x & 0xFFFF0000u);
    f[2] = __uint_as_float(v.y << 16); f[3] = __uint_as_float(v.y & 0xFFFF0000u);
    f[4] = __uint_as_float(v.z << 16); f[5] = __uint_as_float(v.z & 0xFFFF0000u);
    f[6] = __uint_as_float(v.w << 16); f[7] = __uint_as_float(v.w & 0xFFFF0000u);
}
__device__ __forceinline__ void unp4(uint2 v, float* f) {
    f[0] = __uint_as_float(v.x << 16); f[1] = __uint_as_float(v.x & 0xFFFF0000u);
    f[2] = __uint_as_float(v.y << 16); f[3] = __uint_as_float(v.y & 0xFFFF0000u);
}

// ---------------- weight f32 -> bf16 ----------------
__global__ void k_f2bf(const float* __restrict__ src, u16* __restrict__ dst, int n) {
    int i = blockIdx.x * blockDim.x + threadIdx.x;
    if (i < n) dst[i] = f2bf(src[i]);
}

// ---------------- embedding: x = elem_fea @ emb_w + emb_b, concat weights ----------------
__global__ __launch_bounds__(256) void k_embed(
    const float* __restrict__ elem_fea, const float* __restrict__ elem_w,
    const float* __restrict__ emb_w, const float* __restrict__ emb_b,
    float* __restrict__ x)
{
    const int wave = threadIdx.x >> 6, lane = threadIdx.x & 63;
    const int node = blockIdx.x * 4 + wave;
    if (node >= NN) return;
    if (lane < 63) {
        float acc = emb_b[lane];
        const float* fr = elem_fea + (size_t)node * EMBD;
        for (int k = 0; k < EMBD; ++k)
            acc += fr[k] * emb_w[k * 63 + lane];
        x[node * 64 + lane] = acc;
    } else {
        x[node * 64 + 63] = elem_w[node];
    }
}

// ---------------- edge gate: gate[e][h] = LReLU(fea@W1+b1) . w2 (b2 cancels in softmax) ----------------
__global__ __launch_bounds__(1024) void k_edge_gate(
    const float* __restrict__ x, const int* __restrict__ self_idx,
    const int* __restrict__ nbr_idx, const u16* __restrict__ w1,
    const float* __restrict__ w2, const float* __restrict__ b1,
    float* __restrict__ gate_t)
{
    __shared__ u16 sW[128 * 256];     // 64 KB, one head's W1
    __shared__ u16 sfea[128][128];    // [k][edge], 32 KB
    const int tid = threadIdx.x;
    const int e0 = blockIdx.x * 128;
    for (int i = tid; i < 128 * 128; i += 1024) {
        const int e = i >> 7, k = i & 127;
        const int ge = e0 + e;
        float v = 0.f;
        if (ge < NE) {
            const int node = (k < 64) ? self_idx[ge] : nbr_idx[ge];
            v = x[node * 64 + (k & 63)];
        }
        sfea[k][e] = f2bf(v);
    }
    const int lane = tid & 63, w = tid >> 6;
    const int j = lane * 4;
    const int eb = e0 + w * 8;
    for (int h = 0; h < 3; ++h) {
        __syncthreads();
        {
            const uint2* src = (const uint2*)(w1 + h * 128 * 256);
            uint2* dst = (uint2*)sW;
            for (int i = tid; i < 128 * 256 / 4; i += 1024) dst[i] = src[i];
        }
        __syncthreads();
        const float4 w2v = *(const float4*)(w2 + h * 256 + j);
        const float4 b1v = *(const float4*)(b1 + h * 256 + j);
        float acc[8][4];
        #pragma unroll
        for (int e = 0; e < 8; ++e) { acc[e][0] = 0; acc[e][1] = 0; acc[e][2] = 0; acc[e][3] = 0; }
        #pragma unroll 2
        for (int kk = 0; kk < 128; ++kk) {
            float wf[4]; unp4(*(const uint2*)&sW[kk * 256 + j], wf);
            float ff[8]; unp8(*(const uint4*)&sfea[kk][w * 8], ff);
            #pragma unroll
            for (int e = 0; e < 8; ++e) {
                acc[e][0] += ff[e] * wf[0];
                acc[e][1] += ff[e] * wf[1];
                acc[e][2] += ff[e] * wf[2];
                acc[e][3] += ff[e] * wf[3];
            }
        }
        float gp[8];
        #pragma unroll
        for (int e = 0; e < 8; ++e) {
            float s;
            s  = lrelu(acc[e][0] + b1v.x) * w2v.x;
            s += lrelu(acc[e][1] + b1v.y) * w2v.y;
            s += lrelu(acc[e][2] + b1v.z) * w2v.z;
            s += lrelu(acc[e][3] + b1v.w) * w2v.w;
            gp[e] = s;
        }
        #pragma unroll
        for (int off = 32; off; off >>= 1) {
            #pragma unroll
            for (int e = 0; e < 8; ++e) gp[e] += __shfl_xor(gp[e], off, 64);
        }
        if (lane == 0) {
            #pragma unroll
            for (int e = 0; e < 8; ++e)
                if (eb + e < NE) gate_t[(size_t)(eb + e) * 3 + h] = gp[e];
        }
    }
}

// ---------------- segment max ----------------
__global__ void k_seg_max(const float* __restrict__ gate_t, const int* __restrict__ self_idx,
                          u32* __restrict__ gmax)
{
    int e = blockIdx.x * blockDim.x + threadIdx.x;
    if (e >= NE) return;
    int s = self_idx[e] * 3;
    #pragma unroll
    for (int h = 0; h < 3; ++h) atomicMax(&gmax[s + h], encf(gate_t[(size_t)e * 3 + h]));
}

// ---------------- t = w^p * exp(g - gmax); den += t ----------------
__global__ void k_seg_exp(float* __restrict__ gate_t, const int* __restrict__ self_idx,
                          const int* __restrict__ nbr_idx, const float* __restrict__ elem_w,
                          const float* __restrict__ pw, const u32* __restrict__ gmax,
                          float* __restrict__ den)
{
    int e = blockIdx.x * blockDim.x + threadIdx.x;
    if (e >= NE) return;
    int s = self_idx[e] * 3;
    float wgt = elem_w[nbr_idx[e]];
    #pragma unroll
    for (int h = 0; h < 3; ++h) {
        float gm = decf(gmax[s + h]);
        float t = powf(wgt, pw[h]) * expf(gate_t[(size_t)e * 3 + h] - gm);
        gate_t[(size_t)e * 3 + h] = t;
        atomicAdd(&den[s + h], t);
    }
}

// ---------------- edge message + weighted scatter ----------------
__global__ __launch_bounds__(512) void k_edge_msg(
    const float* __restrict__ x, const int* __restrict__ self_idx, const int* __restrict__ nbr_idx,
    const u16* __restrict__ w1, const float* __restrict__ b1,
    const u16* __restrict__ w2, const float* __restrict__ b2,
    const float* __restrict__ tbuf, const float* __restrict__ den,
    float* __restrict__ pooled)
{
    __shared__ u16 sW1[128 * 256];    // 64 KB
    __shared__ u16 sW2[256 * 64];     // 32 KB
    __shared__ u16 sfea[128][64];     // 16 KB
    __shared__ u16 shid[256][72];     // 36 KB
    const int tid = threadIdx.x;
    const int e0 = blockIdx.x * 64;
    for (int i = tid; i < 64 * 128; i += 512) {
        const int e = i >> 7, k = i & 127;
        const int ge = e0 + e;
        float v = 0.f;
        if (ge < NE) {
            const int node = (k < 64) ? self_idx[ge] : nbr_idx[ge];
            v = x[node * 64 + (k & 63)];
        }
        sfea[k][e] = f2bf(v);
    }
    const int lane = tid & 63, w = tid >> 6;
    const int j = lane * 4;
    const int eb = e0 + w * 8;
    int sidx[8];
    #pragma unroll
    for (int e = 0; e < 8; ++e) sidx[e] = (eb + e < NE) ? self_idx[eb + e] : 0;
    float wacc[8];
    #pragma unroll
    for (int e = 0; e < 8; ++e) wacc[e] = 0.f;
    for (int h = 0; h < 3; ++h) {
        __syncthreads();
        for (int i = tid; i < 128 * 256 / 4; i += 512)
            ((uint2*)sW1)[i] = ((const uint2*)(w1 + h * 128 * 256))[i];
        for (int i = tid; i < 256 * 64 / 4; i += 512)
            ((uint2*)sW2)[i] = ((const uint2*)(w2 + h * 256 * 64))[i];
        __syncthreads();
        float acc[8][4];
        #pragma unroll
        for (int e = 0; e < 8; ++e) { acc[e][0] = 0; acc[e][1] = 0; acc[e][2] = 0; acc[e][3] = 0; }
        #pragma unroll 2
        for (int kk = 0; kk < 128; ++kk) {
            float wf[4]; unp4(*(const uint2*)&sW1[kk * 256 + j], wf);
            float ff[8]; unp8(*(const uint4*)&sfea[kk][w * 8], ff);
            #pragma unroll
            for (int e = 0; e < 8; ++e) {
                acc[e][0] += ff[e] * wf[0];
                acc[e][1] += ff[e] * wf[1];
                acc[e][2] += ff[e] * wf[2];
                acc[e][3] += ff[e] * wf[3];
            }
        }
        const float4 b1v = *(const float4*)(b1 + h * 256 + j);
        const float ba[4] = {b1v.x, b1v.y, b1v.z, b1v.w};
        #pragma unroll
        for (int i = 0; i < 4; ++i) {
            uint4 pk;
            pk.x = (u32)f2bf(lrelu(acc[0][i] + ba[i])) | ((u32)f2bf(lrelu(acc[1][i] + ba[i])) << 16);
            pk.y = (u32)f2bf(lrelu(acc[2][i] + ba[i])) | ((u32)f2bf(lrelu(acc[3][i] + ba[i])) << 16);
            pk.z = (u32)f2bf(lrelu(acc[4][i] + ba[i])) | ((u32)f2bf(lrelu(acc[5][i] + ba[i])) << 16);
            pk.w = (u32)f2bf(lrelu(acc[6][i] + ba[i])) | ((u32)f2bf(lrelu(acc[7][i] + ba[i])) << 16);
            *(uint4*)&shid[j + i][w * 8] = pk;
        }
        __syncthreads();
        float acc2[8];
        #pragma unroll
        for (int e = 0; e < 8; ++e) acc2[e] = 0.f;
        #pragma unroll 4
        for (int jj = 0; jj < 256; ++jj) {
            float wv = bf2f(sW2[jj * 64 + lane]);
            float hf[8]; unp8(*(const uint4*)&shid[jj][w * 8], hf);
            #pragma unroll
            for (int e = 0; e < 8; ++e) acc2[e] += hf[e] * wv;
        }
        float b2v = b2[h * 64 + lane];
        #pragma unroll
        for (int e = 0; e < 8; ++e) {
            if (eb + e < NE) {
                float g = tbuf[(size_t)(eb + e) * 3 + h] / (den[sidx[e] * 3 + h] + 1e-10f);
                wacc[e] += g * (acc2[e] + b2v);
            }
        }
    }
    #pragma unroll
    for (int e = 0; e < 8; ++e)
        if (eb + e < NE) atomicAdd(&pooled[(size_t)sidx[e] * 64 + lane], wacc[e] * (1.f / 3.f));
}

// ---------------- residual: x += pooled ----------------
__global__ void k_resid(float* __restrict__ x, const float* __restrict__ pooled) {
    int i = blockIdx.x * blockDim.x + threadIdx.x;
    if (i < NN * 64) x[i] += pooled[i];
}

// ---------------- crystal gate ----------------
__global__ __launch_bounds__(1024) void k_cry_gate(
    const float* __restrict__ x, const u16* __restrict__ w1,
    const float* __restrict__ w2, const float* __restrict__ b1,
    float* __restrict__ cgate)
{
    __shared__ u16 sW[64 * 256];      // 32 KB
    __shared__ u16 sfea[64][128];     // 16 KB
    const int tid = threadIdx.x;
    const int n0 = blockIdx.x * 128;
    for (int i = tid; i < 128 * 64; i += 1024) {
        const int n = i >> 6, k = i & 63;
        float v = (n0 + n < NN) ? x[(size_t)(n0 + n) * 64 + k] : 0.f;
        sfea[k][n] = f2bf(v);
    }
    const int lane = tid & 63, w = tid >> 6;
    const int j = lane * 4;
    const int nb = n0 + w * 8;
    for (int h = 0; h < 3; ++h) {
        __syncthreads();
        {
            const uint2* src = (const uint2*)(w1 + h * 64 * 256);
            uint2* dst = (uint2*)sW;
            for (int i = tid; i < 64 * 256 / 4; i += 1024) dst[i] = src[i];
        }
        __syncthreads();
        const float4 w2v = *(const float4*)(w2 + h * 256 + j);
        const float4 b1v = *(const float4*)(b1 + h * 256 + j);
        float acc[8][4];
        #pragma unroll
        for (int e = 0; e < 8; ++e) { acc[e][0] = 0; acc[e][1] = 0; acc[e][2] = 0; acc[e][3] = 0; }
        #pragma unroll 2
        for (int kk = 0; kk < 64; ++kk) {
            float wf[4]; unp4(*(const uint2*)&sW[kk * 256 + j], wf);
            float ff[8]; unp8(*(const uint4*)&sfea[kk][w * 8], ff);
            #pragma unroll
            for (int e = 0; e < 8; ++e) {
                acc[e][0] += ff[e] * wf[0];
                acc[e][1] += ff[e] * wf[1];
                acc[e][2] += ff[e] * wf[2];
                acc[e][3] += ff[e] * wf[3];
            }
        }
        float gp[8];
        #pragma unroll
        for (int e = 0; e < 8; ++e) {
            float s;
            s  = lrelu(acc[e][0] + b1v.x) * w2v.x;
            s += lrelu(acc[e][1] + b1v.y) * w2v.y;
            s += lrelu(acc[e][2] + b1v.z) * w2v.z;
            s += lrelu(acc[e][3] + b1v.w) * w2v.w;
            gp[e] = s;
        }
        #pragma unroll
        for (int off = 32; off; off >>= 1) {
            #pragma unroll
            for (int e = 0; e < 8; ++e) gp[e] += __shfl_xor(gp[e], off, 64);
        }
        if (lane == 0) {
            #pragma unroll
            for (int e = 0; e < 8; ++e)
                if (nb + e < NN) cgate[(size_t)(nb + e) * 3 + h] = gp[e];
        }
    }
}

__global__ void k_cry_max(const float* __restrict__ cgate, const int* __restrict__ cry_idx,
                          u32* __restrict__ cgmax)
{
    int n = blockIdx.x * blockDim.x + threadIdx.x;
    if (n >= NN) return;
    int c = cry_idx[n] * 3;
    #pragma unroll
    for (int h = 0; h < 3; ++h) atomicMax(&cgmax[c + h], encf(cgate[(size_t)n * 3 + h]));
}

__global__ void k_cry_exp(float* __restrict__ cgate, const int* __restrict__ cry_idx,
                          const float* __restrict__ elem_w, const float* __restrict__ pw,
                          const u32* __restrict__ cgmax, float* __restrict__ cden)
{
    int n = blockIdx.x * blockDim.x + threadIdx.x;
    if (n >= NN) return;
    int c = cry_idx[n] * 3;
    float wgt = elem_w[n];
    #pragma unroll
    for (int h = 0; h < 3; ++h) {
        float gm = decf(cgmax[c + h]);
        float t = powf(wgt, pw[h]) * expf(cgate[(size_t)n * 3 + h] - gm);
        cgate[(size_t)n * 3 + h] = t;
        atomicAdd(&cden[c + h], t);
    }
}

// ---------------- crystal message + scatter to output ----------------
__global__ __launch_bounds__(512) void k_cry_msg(
    const float* __restrict__ x, const int* __restrict__ cry_idx,
    const u16* __restrict__ w1, const float* __restrict__ b1,
    const u16* __restrict__ w2, const float* __restrict__ b2,
    const float* __restrict__ tbuf, const float* __restrict__ cden,
    float* __restrict__ out)
{
    __shared__ u16 sW1[64 * 256];     // 32 KB
    __shared__ u16 sW2[256 * 64];     // 32 KB
    __shared__ u16 sfea[64][64];      // 8 KB
    __shared__ u16 shid[256][72];     // 36 KB
    const int tid = threadIdx.x;
    const int n0 = blockIdx.x * 64;
    for (int i = tid; i < 64 * 64; i += 512) {
        const int n = i >> 6, k = i & 63;
        float v = (n0 + n < NN) ? x[(size_t)(n0 + n) * 64 + k] : 0.f;
        sfea[k][n] = f2bf(v);
    }
    const int lane = tid & 63, w = tid >> 6;
    const int j = lane * 4;
    const int nb = n0 + w * 8;
    int cidx[8];
    #pragma unroll
    for (int e = 0; e < 8; ++e) cidx[e] = (nb + e < NN) ? cry_idx[nb + e] : 0;
    float wacc[8];
    #pragma unroll
    for (int e = 0; e < 8; ++e) wacc[e] = 0.f;
    for (int h = 0; h < 3; ++h) {
        __syncthreads();
        for (int i = tid; i < 64 * 256 / 4; i += 512)
            ((uint2*)sW1)[i] = ((const uint2*)(w1 + h * 64 * 256))[i];
        for (int i = tid; i < 256 * 64 / 4; i += 512)
            ((uint2*)sW2)[i] = ((const uint2*)(w2 + h * 256 * 64))[i];
        __syncthreads();
        float acc[8][4];
        #pragma unroll
        for (int e = 0; e < 8; ++e) { acc[e][0] = 0; acc[e][1] = 0; acc[e][2] = 0; acc[e][3] = 0; }
        #pragma unroll 2
        for (int kk = 0; kk < 64; ++kk) {
            float wf[4]; unp4(*(const uint2*)&sW1[kk * 256 + j], wf);
            float ff[8]; unp8(*(const uint4*)&sfea[kk][w * 8], ff);
            #pragma unroll
            for (int e = 0; e < 8; ++e) {
                acc[e][0] += ff[e] * wf[0];
                acc[e][1] += ff[e] * wf[1];
                acc[e][2] += ff[e] * wf[2];
                acc[e][3] += ff[e] * wf[3];
            }
        }
        const float4 b1v = *(const float4*)(b1 + h * 256 + j);
        const float ba[4] = {b1v.x, b1v.y, b1v.z, b1v.w};
        #pragma unroll
        for (int i = 0; i < 4; ++i) {
            uint4 pk;
            pk.x = (u32)f2bf(lrelu(acc[0][i] + ba[i])) | ((u32)f2bf(lrelu(acc[1][i] + ba[i])) << 16);
            pk.y = (u32)f2bf(lrelu(acc[2][i] + ba[i])) | ((u32)f2bf(lrelu(acc[3][i] + ba[i])) << 16);
            pk.z = (u32)f2bf(lrelu(acc[4][i] + ba[i])) | ((u32)f2bf(lrelu(acc[5][i] + ba[i])) << 16);
            pk.w = (u32)f2bf(lrelu(acc[6][i] + ba[i])) | ((u32)f2bf(lrelu(acc[7][i] + ba[i])) << 16);
            *(uint4*)&shid[j + i][w * 8] = pk;
        }
        __syncthreads();
        float acc2[8];
        #pragma unroll
        for (int e = 0; e < 8; ++e) acc2[e] = 0.f;
        #pragma unroll 4
        for (int jj = 0; jj < 256; ++jj) {
            float wv = bf2f(sW2[jj * 64 + lane]);
            float hf[8]; unp8(*(const uint4*)&shid[jj][w * 8], hf);
            #pragma unroll
            for (int e = 0; e < 8; ++e) acc2[e] += hf[e] * wv;
        }
        float b2v = b2[h * 64 + lane];
        #pragma unroll
        for (int e = 0; e < 8; ++e) {
            if (nb + e < NN) {
                float g = tbuf[(size_t)(nb + e) * 3 + h] / (cden[cidx[e] * 3 + h] + 1e-10f);
                wacc[e] += g * (acc2[e] + b2v);
            }
        }
    }
    #pragma unroll
    for (int e = 0; e < 8; ++e)
        if (nb + e < NN) atomicAdd(&out[(size_t)cidx[e] * 64 + lane], wacc[e] * (1.f / 3.f));
}

extern "C" void kernel_launch(void* const* d_in, const int* in_sizes, int n_in,
                              void* d_out, int out_size, void* d_ws, size_t ws_size,
                              hipStream_t stream)
{
    const float* elem_w   = (const float*)d_in[0];
    const float* elem_fea = (const float*)d_in[1];
    const int*   self_idx = (const int*)d_in[2];
    const int*   nbr_idx  = (const int*)d_in[3];
    const int*   cry_idx  = (const int*)d_in[4];
    const float* emb_w    = (const float*)d_in[5];
    const float* emb_b    = (const float*)d_in[6];
    const float* gg_w1    = (const float*)d_in[7];
    const float* gg_b1    = (const float*)d_in[8];
    const float* gg_w2    = (const float*)d_in[9];
    // d_in[10] g_gate_b2: cancels in scatter-softmax
    const float* gm_w1    = (const float*)d_in[11];
    const float* gm_b1    = (const float*)d_in[12];
    const float* gm_w2    = (const float*)d_in[13];
    const float* gm_b2    = (const float*)d_in[14];
    const float* g_pow    = (const float*)d_in[15];
    const float* cg_w1    = (const float*)d_in[16];
    const float* cg_b1    = (const float*)d_in[17];
    const float* cg_w2    = (const float*)d_in[18];
    // d_in[19] c_gate_b2: cancels
    const float* cm_w1    = (const float*)d_in[20];
    const float* cm_b1    = (const float*)d_in[21];
    const float* cm_w2    = (const float*)d_in[22];
    const float* cm_b2    = (const float*)d_in[23];
    const float* c_pow    = (const float*)d_in[24];

    char* wsp = (char*)d_ws;
    size_t off = 0;
    auto alloc = [&](size_t b) { char* p = wsp + off; off += (b + 255) & ~(size_t)255; return p; };
    float* x      = (float*)alloc((size_t)NN * 64 * 4);
    float* pooled = (float*)alloc((size_t)NN * 64 * 4);
    float* gate_t = (float*)alloc((size_t)NE * 3 * 4);   // also reused as crystal gate buf
    float* den    = (float*)alloc((size_t)NN * 3 * 4);
    u32*   gmax   = (u32*)  alloc((size_t)NN * 3 * 4);
    float* cden   = (float*)alloc((size_t)NC * 3 * 4);
    u32*   cgmax  = (u32*)  alloc((size_t)NC * 3 * 4);
    u16* wg1b = (u16*)alloc((size_t)294912 * 2);
    u16* wm1b = (u16*)alloc((size_t)294912 * 2);
    u16* wm2b = (u16*)alloc((size_t)147456 * 2);
    u16* cg1b = (u16*)alloc((size_t)49152 * 2);
    u16* cm1b = (u16*)alloc((size_t)49152 * 2);
    u16* cm2b = (u16*)alloc((size_t)49152 * 2);

    k_f2bf<<<(294912 + 255) / 256, 256, 0, stream>>>(gg_w1, wg1b, 294912);
    k_f2bf<<<(294912 + 255) / 256, 256, 0, stream>>>(gm_w1, wm1b, 294912);
    k_f2bf<<<(147456 + 255) / 256, 256, 0, stream>>>(gm_w2, wm2b, 147456);
    k_f2bf<<<(49152 + 255) / 256, 256, 0, stream>>>(cg_w1, cg1b, 49152);
    k_f2bf<<<(49152 + 255) / 256, 256, 0, stream>>>(cm_w1, cm1b, 49152);
    k_f2bf<<<(49152 + 255) / 256, 256, 0, stream>>>(cm_w2, cm2b, 49152);

    k_embed<<<(NN + 3) / 4, 256, 0, stream>>>(elem_fea, elem_w, emb_w, emb_b, x);

    for (int l = 0; l < 3; ++l) {
        hipMemsetAsync(gmax, 0, (size_t)NN * 3 * 4, stream);
        hipMemsetAsync(den, 0, (size_t)NN * 3 * 4, stream);
        hipMemsetAsync(pooled, 0, (size_t)NN * 64 * 4, stream);
        k_edge_gate<<<(NE + 127) / 128, 1024, 0, stream>>>(
            x, self_idx, nbr_idx, wg1b + (size_t)l * 3 * 128 * 256,
            gg_w2 + l * 3 * 256, gg_b1 + l * 3 * 256, gate_t);
        k_seg_max<<<(NE + 255) / 256, 256, 0, stream>>>(gate_t, self_idx, gmax);
        k_seg_exp<<<(NE + 255) / 256, 256, 0, stream>>>(
            gate_t, self_idx, nbr_idx, elem_w, g_pow + l * 3, gmax, den);
        k_edge_msg<<<(NE + 63) / 64, 512, 0, stream>>>(
            x, self_idx, nbr_idx, wm1b + (size_t)l * 3 * 128 * 256, gm_b1 + l * 3 * 256,
            wm2b + (size_t)l * 3 * 256 * 64, gm_b2 + l * 3 * 64, gate_t, den, pooled);
        k_resid<<<(NN * 64 + 255) / 256, 256, 0, stream>>>(x, pooled);
    }

    hipMemsetAsync(cgmax, 0, (size_t)NC * 3 * 4, stream);
    hipMemsetAsync(cden, 0, (size_t)NC * 3 * 4, stream);
    hipMemsetAsync(d_out, 0, (size_t)NC * 64 * 4, stream);
    k_cry_gate<<<(NN + 127) / 128, 1024, 0, stream>>>(x, cg1b, cg_w2, cg_b1, gate_t);
    k_cry_max<<<(NN + 255) / 256, 256, 0, stream>>>(gate_t, cry_idx, cgmax);
    k_cry_exp<<<(NN + 255) / 256, 256, 0, stream>>>(gate_t, cry_idx, elem_w, c_pow, cgmax, cden);
    k_cry_msg<<<(NN + 63) / 64, 512, 0, stream>>>(
        x, cry_idx, cm1b, cm_b1, cm2b, cm_b2, gate_t, cden, (float*)d_out);
}

// Round 2
// 7089.461 us; speedup vs baseline: 6.1919x; 6.1919x over previous
//
#include <hip/hip_runtime.h>

#define NN 250000
#define NE 1250000
#define NC 50000
#define EMBD 200

typedef unsigned int u32;
typedef unsigned short u16;
typedef short s16x8 __attribute__((ext_vector_type(8)));
typedef float f32x4 __attribute__((ext_vector_type(4)));

__device__ __forceinline__ u16 f2bf(float f) {
    u32 u = __float_as_uint(f);
    return (u16)((u + 0x7FFFu + ((u >> 16) & 1u)) >> 16);   // RNE
}
__device__ __forceinline__ float lrelu(float v) { return v > 0.f ? v : 0.01f * v; }
__device__ __forceinline__ u32 encf(float f) {
    u32 u = __float_as_uint(f);
    return (u & 0x80000000u) ? ~u : (u | 0x80000000u);
}
__device__ __forceinline__ float decf(u32 k) {
    return __uint_as_float((k & 0x80000000u) ? (k ^ 0x80000000u) : ~k);
}

// ---------- pack W[K][N] f32 -> fragment-major bf16 for mfma_16x16x32 B-operand ----------
// frag f = ks*(N/16)+ng ; lane (q=lane>>4,c=lane&15) holds W[32*ks+8*q+i][16*ng+c], i=0..7
__global__ void k_pack(const float* __restrict__ src, u16* __restrict__ dst,
                       int K, int N, int nheads)
{
    const int t = blockIdx.x * 256 + threadIdx.x;
    const int F = (K / 32) * (N / 16);
    if (t >= nheads * F * 64) return;
    const int lane = t & 63;
    const int fh = t >> 6;
    const int f = fh % F, head = fh / F;
    const int ng = f % (N / 16), ks = f / (N / 16);
    const int q = lane >> 4, c = lane & 15;
    const float* s = src + (size_t)head * K * N;
    u16 o[8];
    #pragma unroll
    for (int i = 0; i < 8; ++i)
        o[i] = f2bf(s[(size_t)(32 * ks + 8 * q + i) * N + 16 * ng + c]);
    uint4 v;
    v.x = (u32)o[0] | ((u32)o[1] << 16);
    v.y = (u32)o[2] | ((u32)o[3] << 16);
    v.z = (u32)o[4] | ((u32)o[5] << 16);
    v.w = (u32)o[6] | ((u32)o[7] << 16);
    *(uint4*)(dst + (size_t)head * K * N + ((size_t)f * 64 + lane) * 8) = v;
}

// ---------- embedding ----------
__global__ __launch_bounds__(256) void k_embed(
    const float* __restrict__ elem_fea, const float* __restrict__ elem_w,
    const float* __restrict__ emb_w, const float* __restrict__ emb_b,
    float* __restrict__ x, u16* __restrict__ xbf)
{
    const int wave = threadIdx.x >> 6, lane = threadIdx.x & 63;
    const int node = blockIdx.x * 4 + wave;
    if (node >= NN) return;
    float acc;
    if (lane < 63) {
        acc = emb_b[lane];
        const float* fr = elem_fea + (size_t)node * EMBD;
        for (int k = 0; k < EMBD; ++k)
            acc += fr[k] * emb_w[k * 63 + lane];
    } else {
        acc = elem_w[node];
    }
    x[(size_t)node * 64 + lane] = acc;
    xbf[(size_t)node * 64 + lane] = f2bf(acc);
}

// ---------- MFMA gate: out[e][h] = sum_col lrelu((fea@W1)[col]+b1[col])*w2[col] ----------
template<int KD, bool GATHER>
__global__ __launch_bounds__(256) void k_gate(
    const u16* __restrict__ xbf, const int* __restrict__ sidx, const int* __restrict__ nidx,
    const u16* __restrict__ w1p, const float* __restrict__ b1g, const float* __restrict__ w2g,
    float* __restrict__ gate_out, int nrows)
{
    constexpr int KS = KD / 32;
    constexpr int RB = KD * 2;      // LDS row bytes
    constexpr int G  = KD / 8;      // 16B granules per row
    __shared__ u16 sA[64 * KD];
    __shared__ float sg[4][64];
    const int tid = threadIdx.x;
    const int r0 = blockIdx.x * 64;
    const int rem = min(64, nrows - r0);

    for (int i = tid; i < 64 * G; i += 256) {
        const int row = i / G, g = i % G;
        const int rr = (row < rem) ? row : 0;
        uint4 v;
        if (GATHER) {
            const int node = (g < G / 2) ? sidx[r0 + rr] : nidx[r0 + rr];
            v = *(const uint4*)(xbf + (size_t)node * 64 + (g & (G / 2 - 1)) * 8);
        } else {
            v = *(const uint4*)(xbf + (size_t)(r0 + rr) * 64 + g * 8);
        }
        *(uint4*)((char*)sA + row * RB + ((g ^ (row & 7)) * 16)) = v;   // T2 swizzle
    }
    __syncthreads();

    const int w = tid >> 6, lane = tid & 63, q = lane >> 4, c = lane & 15;

    for (int h = 0; h < 3; ++h) {
        s16x8 B[KS][4];
        const u16* wp = w1p + (size_t)h * KD * 256;
        #pragma unroll
        for (int ks = 0; ks < KS; ++ks)
            #pragma unroll
            for (int n = 0; n < 4; ++n)
                B[ks][n] = *(const s16x8*)(wp + ((size_t)(ks * 16 + w * 4 + n) * 64 + lane) * 8);

        f32x4 acc[4][4];
        #pragma unroll
        for (int m = 0; m < 4; ++m)
            #pragma unroll
            for (int n = 0; n < 4; ++n) acc[m][n] = 0.f;

        #pragma unroll
        for (int ks = 0; ks < KS; ++ks) {
            s16x8 a[4];
            #pragma unroll
            for (int m = 0; m < 4; ++m) {
                const int row = m * 16 + c;
                a[m] = *(const s16x8*)((const char*)sA + row * RB + (((ks * 4 + q) ^ (row & 7)) * 16));
            }
            #pragma unroll
            for (int n = 0; n < 4; ++n)
                #pragma unroll
                for (int m = 0; m < 4; ++m)
                    acc[m][n] = __builtin_amdgcn_mfma_f32_16x16x32_bf16(a[m], B[ks][n], acc[m][n], 0, 0, 0);
        }

        float part[4][4];
        #pragma unroll
        for (int m = 0; m < 4; ++m)
            #pragma unroll
            for (int r = 0; r < 4; ++r) part[m][r] = 0.f;
        #pragma unroll
        for (int n = 0; n < 4; ++n) {
            const int col = w * 64 + n * 16 + c;
            const float b1v = b1g[h * 256 + col];
            const float w2v = w2g[h * 256 + col];
            #pragma unroll
            for (int m = 0; m < 4; ++m)
                #pragma unroll
                for (int r = 0; r < 4; ++r)
                    part[m][r] += lrelu(acc[m][n][r] + b1v) * w2v;
        }
        #pragma unroll
        for (int off = 1; off < 16; off <<= 1)
            #pragma unroll
            for (int m = 0; m < 4; ++m)
                #pragma unroll
                for (int r = 0; r < 4; ++r)
                    part[m][r] += __shfl_xor(part[m][r], off, 64);
        if (c == 0) {
            #pragma unroll
            for (int m = 0; m < 4; ++m)
                #pragma unroll
                for (int r = 0; r < 4; ++r)
                    sg[w][m * 16 + q * 4 + r] = part[m][r];
        }
        __syncthreads();
        if (tid < rem)
            gate_out[(size_t)(r0 + tid) * 3 + h] = sg[0][tid] + sg[1][tid] + sg[2][tid] + sg[3][tid];
        __syncthreads();
    }
}

// ---------- MFMA msg: hidden=lrelu(fea@W1+b1); out += gate * (hidden@W2+b2)/3 scattered ----------
template<int KD, bool GATHER>
__global__ __launch_bounds__(256) void k_msg(
    const u16* __restrict__ xbf, const int* __restrict__ sidx, const int* __restrict__ nidx,
    const int* __restrict__ scat, const u16* __restrict__ w1p, const float* __restrict__ b1g,
    const u16* __restrict__ w2p, const float* __restrict__ b2g,
    const float* __restrict__ tbuf, const float* __restrict__ den,
    float* __restrict__ outp, int nrows)
{
    constexpr int KS = KD / 32;
    constexpr int RB = KD * 2;
    constexpr int G  = KD / 8;
    __shared__ u16 sA[64 * KD];
    __shared__ u16 sH[64 * 256];
    __shared__ float sgf[64][3];
    __shared__ int ssi[64];
    const int tid = threadIdx.x;
    const int r0 = blockIdx.x * 64;
    const int rem = min(64, nrows - r0);

    for (int i = tid; i < 64 * G; i += 256) {
        const int row = i / G, g = i % G;
        const int rr = (row < rem) ? row : 0;
        uint4 v;
        if (GATHER) {
            const int node = (g < G / 2) ? sidx[r0 + rr] : nidx[r0 + rr];
            v = *(const uint4*)(xbf + (size_t)node * 64 + (g & (G / 2 - 1)) * 8);
        } else {
            v = *(const uint4*)(xbf + (size_t)(r0 + rr) * 64 + g * 8);
        }
        *(uint4*)((char*)sA + row * RB + ((g ^ (row & 7)) * 16)) = v;
    }
    if (tid < 64) ssi[tid] = (tid < rem) ? scat[r0 + tid] : 0;
    if (tid < 192) {
        const int row = tid / 3, h = tid % 3;
        if (row < rem) {
            const int s = scat[r0 + row] * 3 + h;
            sgf[row][h] = tbuf[(size_t)(r0 + row) * 3 + h] / (den[s] + 1e-10f);
        }
    }
    __syncthreads();

    const int w = tid >> 6, lane = tid & 63, q = lane >> 4, c = lane & 15;
    float wacc[4][4];
    #pragma unroll
    for (int m = 0; m < 4; ++m)
        #pragma unroll
        for (int r = 0; r < 4; ++r) wacc[m][r] = 0.f;

    for (int h = 0; h < 3; ++h) {
        // GEMM1: fea @ W1
        s16x8 B[KS][4];
        const u16* wp = w1p + (size_t)h * KD * 256;
        #pragma unroll
        for (int ks = 0; ks < KS; ++ks)
            #pragma unroll
            for (int n = 0; n < 4; ++n)
                B[ks][n] = *(const s16x8*)(wp + ((size_t)(ks * 16 + w * 4 + n) * 64 + lane) * 8);

        f32x4 acc[4][4];
        #pragma unroll
        for (int m = 0; m < 4; ++m)
            #pragma unroll
            for (int n = 0; n < 4; ++n) acc[m][n] = 0.f;

        #pragma unroll
        for (int ks = 0; ks < KS; ++ks) {
            s16x8 a[4];
            #pragma unroll
            for (int m = 0; m < 4; ++m) {
                const int row = m * 16 + c;
                a[m] = *(const s16x8*)((const char*)sA + row * RB + (((ks * 4 + q) ^ (row & 7)) * 16));
            }
            #pragma unroll
            for (int n = 0; n < 4; ++n)
                #pragma unroll
                for (int m = 0; m < 4; ++m)
                    acc[m][n] = __builtin_amdgcn_mfma_f32_16x16x32_bf16(a[m], B[ks][n], acc[m][n], 0, 0, 0);
        }
        // hidden -> sH (bf16, swizzled)
        #pragma unroll
        for (int n = 0; n < 4; ++n) {
            const int col = w * 64 + n * 16 + c;
            const float b1v = b1g[h * 256 + col];
            const int gr = col >> 3;
            #pragma unroll
            for (int m = 0; m < 4; ++m)
                #pragma unroll
                for (int r = 0; r < 4; ++r) {
                    const int row = m * 16 + q * 4 + r;
                    *(u16*)((char*)sH + row * 512 + ((gr ^ (row & 7)) * 16) + (col & 7) * 2) =
                        f2bf(lrelu(acc[m][n][r] + b1v));
                }
        }
        __syncthreads();
        // GEMM2: hidden @ W2
        s16x8 B2[8];
        #pragma unroll
        for (int ks = 0; ks < 8; ++ks)
            B2[ks] = *(const s16x8*)(w2p + (size_t)h * 256 * 64 + ((size_t)(ks * 4 + w) * 64 + lane) * 8);
        f32x4 acc2[4];
        #pragma unroll
        for (int m = 0; m < 4; ++m) acc2[m] = 0.f;
        #pragma unroll
        for (int ks = 0; ks < 8; ++ks) {
            #pragma unroll
            for (int m = 0; m < 4; ++m) {
                const int row = m * 16 + c;
                s16x8 a = *(const s16x8*)((const char*)sH + row * 512 + (((ks * 4 + q) ^ (row & 7)) * 16));
                acc2[m] = __builtin_amdgcn_mfma_f32_16x16x32_bf16(a, B2[ks], acc2[m], 0, 0, 0);
            }
        }
        const float b2v = b2g[h * 64 + w * 16 + c];
        #pragma unroll
        for (int m = 0; m < 4; ++m)
            #pragma unroll
            for (int r = 0; r < 4; ++r) {
                const int row = m * 16 + q * 4 + r;
                wacc[m][r] += (acc2[m][r] + b2v) * sgf[row][h];
            }
        __syncthreads();
    }
    #pragma unroll
    for (int m = 0; m < 4; ++m)
        #pragma unroll
        for (int r = 0; r < 4; ++r) {
            const int row = m * 16 + q * 4 + r;
            if (row < rem)
                atomicAdd(&outp[(size_t)ssi[row] * 64 + w * 16 + c], wacc[m][r] * (1.f / 3.f));
        }
}

// ---------- softmax aux ----------
__global__ void k_seg_max(const float* __restrict__ gate_t, const int* __restrict__ idx,
                          u32* __restrict__ gmax, int n)
{
    int e = blockIdx.x * blockDim.x + threadIdx.x;
    if (e >= n) return;
    int s = idx[e] * 3;
    #pragma unroll
    for (int h = 0; h < 3; ++h) atomicMax(&gmax[s + h], encf(gate_t[(size_t)e * 3 + h]));
}

// wsrc: per-row weight = elem_w[wi[e]] (edges: nbr node; crystal: the node itself)
__global__ void k_seg_exp(float* __restrict__ gate_t, const int* __restrict__ idx,
                          const int* __restrict__ wi, const float* __restrict__ elem_w,
                          const float* __restrict__ pw, const u32* __restrict__ gmax,
                          float* __restrict__ den, int n)
{
    int e = blockIdx.x * blockDim.x + threadIdx.x;
    if (e >= n) return;
    int s = idx[e] * 3;
    float wgt = elem_w[wi ? wi[e] : e];
    #pragma unroll
    for (int h = 0; h < 3; ++h) {
        float gm = decf(gmax[s + h]);
        float t = powf(wgt, pw[h]) * expf(gate_t[(size_t)e * 3 + h] - gm);
        gate_t[(size_t)e * 3 + h] = t;
        atomicAdd(&den[s + h], t);
    }
}

// ---------- refresh bf16 mirror ----------
__global__ void k_mirror(const float* __restrict__ x, u16* __restrict__ xbf, int n4) {
    int i = blockIdx.x * 256 + threadIdx.x;
    if (i >= n4) return;
    float4 v = *(const float4*)(x + (size_t)i * 4);
    uint2 o;
    o.x = (u32)f2bf(v.x) | ((u32)f2bf(v.y) << 16);
    o.y = (u32)f2bf(v.z) | ((u32)f2bf(v.w) << 16);
    *(uint2*)(xbf + (size_t)i * 4) = o;
}

extern "C" void kernel_launch(void* const* d_in, const int* in_sizes, int n_in,
                              void* d_out, int out_size, void* d_ws, size_t ws_size,
                              hipStream_t stream)
{
    const float* elem_w   = (const float*)d_in[0];
    const float* elem_fea = (const float*)d_in[1];
    const int*   self_idx = (const int*)d_in[2];
    const int*   nbr_idx  = (const int*)d_in[3];
    const int*   cry_idx  = (const int*)d_in[4];
    const float* emb_w    = (const float*)d_in[5];
    const float* emb_b    = (const float*)d_in[6];
    const float* gg_w1    = (const float*)d_in[7];
    const float* gg_b1    = (const float*)d_in[8];
    const float* gg_w2    = (const float*)d_in[9];
    // d_in[10] g_gate_b2 cancels in scatter-softmax
    const float* gm_w1    = (const float*)d_in[11];
    const float* gm_b1    = (const float*)d_in[12];
    const float* gm_w2    = (const float*)d_in[13];
    const float* gm_b2    = (const float*)d_in[14];
    const float* g_pow    = (const float*)d_in[15];
    const float* cg_w1    = (const float*)d_in[16];
    const float* cg_b1    = (const float*)d_in[17];
    const float* cg_w2    = (const float*)d_in[18];
    // d_in[19] c_gate_b2 cancels
    const float* cm_w1    = (const float*)d_in[20];
    const float* cm_b1    = (const float*)d_in[21];
    const float* cm_w2    = (const float*)d_in[22];
    const float* cm_b2    = (const float*)d_in[23];
    const float* c_pow    = (const float*)d_in[24];

    char* wsp = (char*)d_ws;
    size_t off = 0;
    auto alloc = [&](size_t b) { char* p = wsp + off; off += (b + 255) & ~(size_t)255; return p; };
    float* x      = (float*)alloc((size_t)NN * 64 * 4);
    u16*   xbf    = (u16*)  alloc((size_t)NN * 64 * 2);
    float* gate_t = (float*)alloc((size_t)NE * 3 * 4);
    float* den    = (float*)alloc((size_t)NN * 3 * 4);
    u32*   gmax   = (u32*)  alloc((size_t)NN * 3 * 4);
    float* cden   = (float*)alloc((size_t)NC * 3 * 4);
    u32*   cgmax  = (u32*)  alloc((size_t)NC * 3 * 4);
    u16* wg1p = (u16*)alloc((size_t)9 * 128 * 256 * 2);
    u16* wm1p = (u16*)alloc((size_t)9 * 128 * 256 * 2);
    u16* wm2p = (u16*)alloc((size_t)9 * 256 * 64 * 2);
    u16* cg1p = (u16*)alloc((size_t)3 * 64 * 256 * 2);
    u16* cm1p = (u16*)alloc((size_t)3 * 64 * 256 * 2);
    u16* cm2p = (u16*)alloc((size_t)3 * 256 * 64 * 2);

    auto pack = [&](const float* s, u16* d, int K, int N, int H) {
        int tot = H * (K / 32) * (N / 16) * 64;
        k_pack<<<(tot + 255) / 256, 256, 0, stream>>>(s, d, K, N, H);
    };
    pack(gg_w1, wg1p, 128, 256, 9);
    pack(gm_w1, wm1p, 128, 256, 9);
    pack(gm_w2, wm2p, 256, 64, 9);
    pack(cg_w1, cg1p, 64, 256, 3);
    pack(cm_w1, cm1p, 64, 256, 3);
    pack(cm_w2, cm2p, 256, 64, 3);

    k_embed<<<(NN + 3) / 4, 256, 0, stream>>>(elem_fea, elem_w, emb_w, emb_b, x, xbf);

    const int GE = (NE + 63) / 64;
    for (int l = 0; l < 3; ++l) {
        hipMemsetAsync(gmax, 0, (size_t)NN * 3 * 4, stream);
        hipMemsetAsync(den, 0, (size_t)NN * 3 * 4, stream);
        k_gate<128, true><<<GE, 256, 0, stream>>>(
            xbf, self_idx, nbr_idx, wg1p + (size_t)l * 3 * 128 * 256,
            gg_b1 + l * 768, gg_w2 + l * 768, gate_t, NE);
        k_seg_max<<<(NE + 255) / 256, 256, 0, stream>>>(gate_t, self_idx, gmax, NE);
        k_seg_exp<<<(NE + 255) / 256, 256, 0, stream>>>(
            gate_t, self_idx, nbr_idx, elem_w, g_pow + l * 3, gmax, den, NE);
        // scatter directly into x (residual); GEMM A reads go through stale xbf mirror
        k_msg<128, true><<<GE, 256, 0, stream>>>(
            xbf, self_idx, nbr_idx, self_idx, wm1p + (size_t)l * 3 * 128 * 256,
            gm_b1 + l * 768, wm2p + (size_t)l * 3 * 256 * 64, gm_b2 + l * 192,
            gate_t, den, x, NE);
        k_mirror<<<(NN * 64 / 4 + 255) / 256, 256, 0, stream>>>(x, xbf, NN * 64 / 4);
    }

    hipMemsetAsync(cgmax, 0, (size_t)NC * 3 * 4, stream);
    hipMemsetAsync(cden, 0, (size_t)NC * 3 * 4, stream);
    hipMemsetAsync(d_out, 0, (size_t)NC * 64 * 4, stream);
    const int GN = (NN + 63) / 64;
    k_gate<64, false><<<GN, 256, 0, stream>>>(
        xbf, nullptr, nullptr, cg1p, cg_b1, cg_w2, gate_t, NN);
    k_seg_max<<<(NN + 255) / 256, 256, 0, stream>>>(gate_t, cry_idx, cgmax, NN);
    k_seg_exp<<<(NN + 255) / 256, 256, 0, stream>>>(
        gate_t, cry_idx, nullptr, elem_w, c_pow, cgmax, cden, NN);
    k_msg<64, false><<<GN, 256, 0, stream>>>(
        xbf, nullptr, nullptr, cry_idx, cm1p, cm_b1, cm2p, cm_b2,
        gate_t, cden, (float*)d_out, NN);
}